// Round 13
// baseline (246.285 us; speedup 1.0000x reference)
//
#include <hip/hip_runtime.h>
#include <hip/hip_fp16.h>

#define NEG_SLOPE 0.2f

typedef _Float16 f16x8 __attribute__((ext_vector_type(8)));
typedef float f32x4 __attribute__((ext_vector_type(4)));

// ================= prologue kernels =================

// deg atomics | bsum[l][f]=sum_h bias | WABall[l][k][j] = sum_f W[l][k][h*64+f]*a[h][f]
__global__ __launch_bounds__(256) void k_pro(
        const int* __restrict__ dst, int* __restrict__ deg,
        const float* __restrict__ W, const float* __restrict__ al,
        const float* __restrict__ ar, const float* __restrict__ bias,
        float* __restrict__ bsum, float* __restrict__ WABall, int ne) {
    int i = blockIdx.x * blockDim.x + threadIdx.x;
    if (i < ne) { atomicAdd(&deg[dst[i]], 1); return; }
    int j = i - ne;
    if (j < 256) {
        int l = j >> 6, f = j & 63;
        float s = 0.f;
        #pragma unroll
        for (int h = 0; h < 4; ++h) s += bias[(l << 8) + h * 64 + f];
        bsum[j] = s;
        return;
    }
    int j2 = j - 256;
    if (j2 < 2048) {                      // WABall, flat ((l*64+k)*8+jj)
        int l = j2 >> 9, r = j2 & 511, k = r >> 3, jj = r & 7, hh = jj & 3;
        const float* wrow = W + (l << 14) + (k << 8) + hh * 64;
        const float* av = ((jj < 4) ? al : ar) + (l << 8) + hh * 64;
        float s = 0.f;
        #pragma unroll 8
        for (int f = 0; f < 64; ++f) s = fmaf(wrow[f], av[f], s);
        WABall[j2] = s;
    }
}

// Pack k_trans B-frags | WABf0 frags | cl consts (unchanged from R12)
__global__ __launch_bounds__(256) void k_packT(
        const float* __restrict__ W, const float* __restrict__ WABall,
        const float* __restrict__ bsum,
        _Float16* __restrict__ Bf, _Float16* __restrict__ WABf0,
        float* __restrict__ cl) {
    int i = blockIdx.x * blockDim.x + threadIdx.x;
    if (i < 4 * 20480) {
        int l = i / 20480, r = i % 20480;
        int j = r & 7, lane = (r >> 3) & 63, kc = (r >> 9) & 7, ct = r >> 12;
        int k = kc * 32 + ((lane >> 4) << 3) + j;
        int c = ct * 16 + (lane & 15);
        int fi = k & 63, hh = k >> 6;
        float v = 0.f;
        if (c < 64) {
            v = W[(l << 14) + (fi << 8) + hh * 64 + c];
        } else if (c < 72 && l < 3) {
            int jj = c - 64;
            const float* wr = W + (l << 14) + (fi << 8) + hh * 64;
            const float* wa = WABall + (((l + 1) * 64) << 3) + jj;
            float s = 0.f;
            #pragma unroll 8
            for (int fo = 0; fo < 64; ++fo) s = fmaf(wr[fo], wa[fo << 3], s);
            v = s;
        }
        Bf[i] = (_Float16)v;
        return;
    }
    int i2 = i - 4 * 20480;
    if (i2 < 1024) {
        int j = i2 & 7, lane = (i2 >> 3) & 63, kc = i2 >> 9;
        int k = kc * 32 + ((lane >> 4) << 3) + j;
        int col = lane & 15;
        float v = (col < 8) ? WABall[(k << 3) + col] : 0.f;
        WABf0[i2] = (_Float16)v;
        return;
    }
    int i3 = i2 - 1024;
    if (i3 < 24) {
        int l = i3 >> 3, jj = i3 & 7;
        const float* wa = WABall + (((l + 1) * 64) << 3) + jj;
        float s = 0.f;
        #pragma unroll 8
        for (int fo = 0; fo < 64; ++fo) s = fmaf(bsum[l * 64 + fo], wa[fo << 3], s);
        cl[l * 8 + jj] = s;
    }
}

#define SCB 2048
__global__ __launch_bounds__(256) void k_scan1(const int* __restrict__ deg,
                                               int* __restrict__ bsums, int n) {
    __shared__ int wsum[4];
    int b = blockIdx.x, t = threadIdx.x;
    int i0 = b * SCB + t * 8;
    int s = 0;
    #pragma unroll
    for (int j = 0; j < 8; ++j) { int i = i0 + j; if (i < n) s += deg[i]; }
    #pragma unroll
    for (int m = 1; m < 64; m <<= 1) s += __shfl_xor(s, m);
    if ((t & 63) == 0) wsum[t >> 6] = s;
    __syncthreads();
    if (t == 0) bsums[b] = wsum[0] + wsum[1] + wsum[2] + wsum[3];
}

__global__ __launch_bounds__(256) void k_scan23(const int* __restrict__ deg,
                                                const int* __restrict__ bsums,
                                                int* __restrict__ rowptr,
                                                int* __restrict__ cursor,
                                                int n, int nb) {
    __shared__ int woff[4];
    __shared__ int boffs;
    int b = blockIdx.x, t = threadIdx.x, lane = t & 63, w = t >> 6;
    if (t < 64) {
        int v = (lane < nb) ? bsums[lane] : 0;
        int s = v;
        #pragma unroll
        for (int m = 1; m < 64; m <<= 1) {
            int y = __shfl_up(s, m);
            if (lane >= m) s += y;
        }
        if (lane == b) boffs = s - v;
        if (b == 0 && lane == nb - 1) rowptr[n] = s;
    }
    __syncthreads();
    int i0 = b * SCB + t * 8;
    int v[8]; int s8 = 0;
    #pragma unroll
    for (int j = 0; j < 8; ++j) { int i = i0 + j; v[j] = (i < n) ? deg[i] : 0; s8 += v[j]; }
    int s = s8;
    #pragma unroll
    for (int m = 1; m < 64; m <<= 1) { int y = __shfl_up(s, m); if (lane >= m) s += y; }
    if (lane == 63) woff[w] = s;
    __syncthreads();
    int wo = 0;
    #pragma unroll
    for (int k = 0; k < 4; ++k) if (k < w) wo += woff[k];
    int excl = boffs + wo + s - s8;
    #pragma unroll
    for (int j = 0; j < 8; ++j) {
        int i = i0 + j;
        if (i < n) { rowptr[i] = excl; cursor[i] = excl; }
        excl += v[j];
    }
}

__global__ __launch_bounds__(256) void k_scatter(const int* __restrict__ src,
                                                 const int* __restrict__ dst,
                                                 int* __restrict__ cursor,
                                                 int* __restrict__ csr_src, int ne) {
    int e = blockIdx.x * blockDim.x + threadIdx.x;
    if (e >= ne) return;
    int pos = atomicAdd(&cursor[dst[e]], 1);
    csr_src[pos] = src[e];
}

// ================= layer kernels =================

// k0: x16 = (f16)feat, el/er_0 = feat . WAB_0 via 2 MFMA
__global__ __launch_bounds__(256) void k0(
        const float* __restrict__ feat, const _Float16* __restrict__ WABf0,
        _Float16* __restrict__ x16, float* __restrict__ el, float* __restrict__ er,
        int n) {
    int t = threadIdx.x, w = t >> 6, lane = t & 63;
    int r0 = blockIdx.x * 64 + w * 16;
    if (r0 >= n) return;
    int m = lane & 15, kb = lane >> 4;
    int gr = r0 + m;

    f16x8 A0, A1;
    if (gr < n) {
        const float* hp = feat + (size_t)gr * 64 + kb * 8;
        float4 p0 = *(const float4*)(hp);
        float4 p1 = *(const float4*)(hp + 4);
        float4 q0 = *(const float4*)(hp + 32);
        float4 q1 = *(const float4*)(hp + 36);
        A0[0] = (_Float16)p0.x; A0[1] = (_Float16)p0.y;
        A0[2] = (_Float16)p0.z; A0[3] = (_Float16)p0.w;
        A0[4] = (_Float16)p1.x; A0[5] = (_Float16)p1.y;
        A0[6] = (_Float16)p1.z; A0[7] = (_Float16)p1.w;
        A1[0] = (_Float16)q0.x; A1[1] = (_Float16)q0.y;
        A1[2] = (_Float16)q0.z; A1[3] = (_Float16)q0.w;
        A1[4] = (_Float16)q1.x; A1[5] = (_Float16)q1.y;
        A1[6] = (_Float16)q1.z; A1[7] = (_Float16)q1.w;
    } else {
        #pragma unroll
        for (int j = 0; j < 8; ++j) { A0[j] = (_Float16)0.f; A1[j] = (_Float16)0.f; }
    }

    {
        f16x8 wb0 = *(const f16x8*)(WABf0 + lane * 8);
        f16x8 wb1 = *(const f16x8*)(WABf0 + 512 + lane * 8);
        f32x4 e; e[0] = 0.f; e[1] = 0.f; e[2] = 0.f; e[3] = 0.f;
        e = __builtin_amdgcn_mfma_f32_16x16x32_f16(A0, wb0, e, 0, 0, 0);
        e = __builtin_amdgcn_mfma_f32_16x16x32_f16(A1, wb1, e, 0, 0, 0);
        if (m < 8) {
            float* dp = (m < 4) ? el : er;
            #pragma unroll
            for (int r = 0; r < 4; ++r) {
                int g2 = r0 + kb * 4 + r;
                if (g2 < n) dp[(size_t)g2 * 4 + (m & 3)] = e[r];
            }
        }
    }

    if (gr < n) {
        *(f16x8*)(x16 + (size_t)gr * 64 + kb * 8) = A0;
        *(f16x8*)(x16 + (size_t)gr * 64 + 32 + kb * 8) = A1;
    }
}

// k_agg2: single-pass edge softmax + raw-x gather, TWO edges per iteration:
// lane = (half<<5)|q; pair-slot i = 2p+half; lane reads uint = cols {2q,2q+1}
// of x16[s_i]. Combine halves via 8 shfl_xor(32). Pad slots to 24/96 so
// 2-pair unrolled groups may overreach with {ee=0, s=valid}.
__global__ __launch_bounds__(256) void k_agg2(
        const int* __restrict__ rowptr, const int* __restrict__ csr_src,
        const float* __restrict__ el, const float* __restrict__ er,
        const _Float16* __restrict__ x16, _Float16* __restrict__ agg, int n) {
    __shared__ float lds_ee[4][96];
    __shared__ int   lds_s[4][24];
    int wid  = (int)((blockIdx.x * blockDim.x + threadIdx.x) >> 6);
    int w    = (threadIdx.x >> 6) & 3;
    int lane = threadIdx.x & 63;
    if (wid >= n) return;
    int d = wid;
    int rbeg = rowptr[d], rend = rowptr[d + 1];
    if (rend == rbeg) {
        *(uint2*)(agg + (size_t)d * 256 + lane * 4) = make_uint2(0u, 0u);
        return;
    }

    int ei = lane >> 2, hh = lane & 3;
    int q = lane & 31, half = lane >> 5;
    float erh = er[(size_t)d * 4 + hh];

    int idx0 = rbeg + ei;
    bool v0 = idx0 < rend;
    int s0 = v0 ? csr_src[idx0] : 0;
    int sfb = __shfl(s0, 0);
    // pad slots (written once; tail chunks rewrite only 0..15)
    if (lane < 32) lds_ee[w][64 + lane] = 0.f;
    if (lane < 8)  lds_s[w][16 + lane] = sfb;

    float ee0 = 0.f;
    if (v0) {
        float x = el[(size_t)s0 * 4 + hh] + erh;
        x = x > 0.f ? x : NEG_SLOPE * x;
        ee0 = __expf(x);
    }
    float dsum = ee0;
    float2 acc[4];
    #pragma unroll
    for (int h = 0; h < 4; ++h) acc[h] = make_float2(0.f, 0.f);
    lds_ee[w][lane] = ee0;
    if (hh == 0) lds_s[w][ei] = v0 ? s0 : sfb;
    {
        int csz = min(16, rend - rbeg);
        int np = (csz + 1) >> 1;           // pairs
        for (int p0 = 0; p0 < np; p0 += 2) {
            #pragma unroll
            for (int j = 0; j < 2; ++j) {
                int i = 2 * (p0 + j) + half;          // <= 2*np+1 <= 17 < 24
                float4 ee4 = *(float4*)&lds_ee[w][i * 4];
                int s = lds_s[w][i];
                unsigned u = *(const unsigned*)(x16 + (size_t)s * 64 + q * 2);
                float2 xv = __half22float2(*(__half2*)&u);
                acc[0].x += ee4.x * xv.x; acc[0].y += ee4.x * xv.y;
                acc[1].x += ee4.y * xv.x; acc[1].y += ee4.y * xv.y;
                acc[2].x += ee4.z * xv.x; acc[2].y += ee4.z * xv.y;
                acc[3].x += ee4.w * xv.x; acc[3].y += ee4.w * xv.y;
            }
        }
    }
    for (int base = rbeg + 16; base < rend; base += 16) {
        int idx = base + ei;
        int e16 = min(16, rend - base);
        float ee = 0.f;
        if (idx < rend) {
            int s = csr_src[idx];
            float x = el[(size_t)s * 4 + hh] + erh;
            x = x > 0.f ? x : NEG_SLOPE * x;
            ee = __expf(x);
            if (hh == 0) lds_s[w][ei] = s;
        }
        dsum += ee;
        lds_ee[w][lane] = ee;   // all 16 slots rewritten; invalid lanes -> 0
        int np = (e16 + 1) >> 1;
        for (int p0 = 0; p0 < np; p0 += 2) {
            #pragma unroll
            for (int j = 0; j < 2; ++j) {
                int i = 2 * (p0 + j) + half;
                float4 ee4 = *(float4*)&lds_ee[w][i * 4];
                int s = lds_s[w][i];                  // stale s ok: ee=0
                unsigned u = *(const unsigned*)(x16 + (size_t)s * 64 + q * 2);
                float2 xv = __half22float2(*(__half2*)&u);
                acc[0].x += ee4.x * xv.x; acc[0].y += ee4.x * xv.y;
                acc[1].x += ee4.y * xv.x; acc[1].y += ee4.y * xv.y;
                acc[2].x += ee4.z * xv.x; acc[2].y += ee4.z * xv.y;
                acc[3].x += ee4.w * xv.x; acc[3].y += ee4.w * xv.y;
            }
        }
    }
    #pragma unroll
    for (int msk = 4; msk < 64; msk <<= 1) dsum += __shfl_xor(dsum, msk);
    float dh0 = __shfl(dsum, 0), dh1 = __shfl(dsum, 1);
    float dh2 = __shfl(dsum, 2), dh3 = __shfl(dsum, 3);
    // combine halves
    #pragma unroll
    for (int h = 0; h < 4; ++h) {
        acc[h].x += __shfl_xor(acc[h].x, 32);
        acc[h].y += __shfl_xor(acc[h].y, 32);
    }
    if (half == 0) {
        float rd0 = 1.f / dh0, rd1 = 1.f / dh1, rd2 = 1.f / dh2, rd3 = 1.f / dh3;
        _Float16* ap = agg + (size_t)d * 256 + q * 2;
        __half2 v0h = __floats2half2_rn(acc[0].x * rd0, acc[0].y * rd0);
        __half2 v1h = __floats2half2_rn(acc[1].x * rd1, acc[1].y * rd1);
        __half2 v2h = __floats2half2_rn(acc[2].x * rd2, acc[2].y * rd2);
        __half2 v3h = __floats2half2_rn(acc[3].x * rd3, acc[3].y * rd3);
        *(__half2*)(ap)       = v0h;
        *(__half2*)(ap + 64)  = v1h;
        *(__half2*)(ap + 128) = v2h;
        *(__half2*)(ap + 192) = v3h;
    }
}

// k_trans: h_next = agg . blockdiag(W_l) + bsum (+ next-layer el/er via EW)
__global__ __launch_bounds__(256) void k_trans(
        const _Float16* __restrict__ agg, const _Float16* __restrict__ Bf,
        const float* __restrict__ bsum, const float* __restrict__ cl,
        _Float16* __restrict__ x16, float* __restrict__ el, float* __restrict__ er,
        float* __restrict__ outF, int n, int last) {
    int t = threadIdx.x, w = t >> 6, lane = t & 63;
    int r0 = blockIdx.x * 64 + w * 16;
    if (r0 >= n) return;
    int m = lane & 15, kb = lane >> 4;
    int gr = r0 + m;

    f16x8 A[8];
    if (gr < n) {
        const _Float16* ap = agg + (size_t)gr * 256 + kb * 8;
        #pragma unroll
        for (int kc = 0; kc < 8; ++kc) A[kc] = *(const f16x8*)(ap + kc * 32);
    } else {
        #pragma unroll
        for (int kc = 0; kc < 8; ++kc)
            #pragma unroll
            for (int j = 0; j < 8; ++j) A[kc][j] = (_Float16)0.f;
    }

    #pragma unroll
    for (int ct = 0; ct < 5; ++ct) {
        if (ct == 4 && last) break;
        f32x4 dd; dd[0] = 0.f; dd[1] = 0.f; dd[2] = 0.f; dd[3] = 0.f;
        #pragma unroll
        for (int kc = 0; kc < 8; ++kc) {
            f16x8 b = *(const f16x8*)(Bf + ((ct * 8 + kc) * 64 + lane) * 8);
            dd = __builtin_amdgcn_mfma_f32_16x16x32_f16(A[kc], b, dd, 0, 0, 0);
        }
        if (ct < 4) {
            int col = ct * 16 + m;
            float bv = bsum[col];
            #pragma unroll
            for (int r = 0; r < 4; ++r) {
                int g2 = r0 + kb * 4 + r;
                if (g2 < n) {
                    if (last) outF[(size_t)g2 * 64 + col] = dd[r] + bv;
                    else      x16[(size_t)g2 * 64 + col] = (_Float16)(dd[r] + bv);
                }
            }
        } else if (m < 8) {
            float cv = cl[m];
            float* dp = (m < 4) ? el : er;
            #pragma unroll
            for (int r = 0; r < 4; ++r) {
                int g2 = r0 + kb * 4 + r;
                if (g2 < n) dp[(size_t)g2 * 4 + (m & 3)] = dd[r] + cv;
            }
        }
    }
}

// ================= launcher =================

extern "C" void kernel_launch(void* const* d_in, const int* in_sizes, int n_in,
                              void* d_out, int out_size, void* d_ws, size_t ws_size,
                              hipStream_t stream) {
    const float* feat = (const float*)d_in[0];
    const float* W    = (const float*)d_in[1];
    const float* al   = (const float*)d_in[2];
    const float* ar   = (const float*)d_in[3];
    const float* bias = (const float*)d_in[4];
    const int*   src  = (const int*)d_in[5];
    const int*   dst  = (const int*)d_in[6];
    float* out = (float*)d_out;

    const int N = in_sizes[0] / 64;   // 50000
    const int E = in_sizes[5];        // 500000
    const int L = 4;

    // workspace carve (float units)
    float* ws = (float*)d_ws;
    _Float16* agg = (_Float16*)ws;                         // N*256 halves
    _Float16* x16 = (_Float16*)(ws + (size_t)N * 128);     // N*64 halves
    float* el     = ws + (size_t)N * 160;                  // N*4
    float* er     = el + (size_t)N * 4;                    // N*4
    float* bsum   = er + (size_t)N * 4;                    // 256
    float* WABall = bsum + 256;                            // 2048
    float* cl     = WABall + 2048;                         // 32
    _Float16* Bf    = (_Float16*)(cl + 32);                // 4*20480 halves
    _Float16* WABf0 = (_Float16*)((float*)Bf + 40960);     // 1024 halves
    int* rowptr  = (int*)((float*)WABf0 + 512);            // N+1
    int* cursor  = rowptr + (N + 1);                       // N
    int* deg     = cursor + N;                             // N
    int* csr_src = deg + N;                                // E
    int* bsums   = csr_src + E;                            // 32

    const int NB = (N + SCB - 1) / SCB;                    // 25

    // ---- prologue ----
    hipMemsetAsync(deg, 0, (size_t)N * sizeof(int), stream);
    int pro_total = E + 256 + 2048;
    k_pro<<<(pro_total + 255) / 256, 256, 0, stream>>>(
        dst, deg, W, al, ar, bias, bsum, WABall, E);
    k_packT<<<(4 * 20480 + 1024 + 24 + 255) / 256, 256, 0, stream>>>(
        W, WABall, bsum, Bf, WABf0, cl);
    k_scan1<<<NB, 256, 0, stream>>>(deg, bsums, N);
    k_scan23<<<NB, 256, 0, stream>>>(deg, bsums, rowptr, cursor, N, NB);
    k_scatter<<<(E + 255) / 256, 256, 0, stream>>>(src, dst, cursor, csr_src, E);

    // ---- layer 0 input ----
    k0<<<(N + 63) / 64, 256, 0, stream>>>(feat, WABf0, x16, el, er, N);

    // ---- layers ----
    for (int l = 0; l < L; ++l) {
        int last = (l == L - 1);
        k_agg2<<<((size_t)N * 64 + 255) / 256, 256, 0, stream>>>(
            rowptr, csr_src, el, er, x16, agg, N);
        k_trans<<<(N + 63) / 64, 256, 0, stream>>>(
            agg, Bf + (size_t)l * 20480, bsum + (size_t)l * 64,
            cl + (size_t)(l < 3 ? l : 0) * 8,
            x16, el, er, out, N, last);
    }
}

// Round 14
// 232.347 us; speedup vs baseline: 1.0600x; 1.0600x over previous
//
#include <hip/hip_runtime.h>
#include <hip/hip_fp16.h>

#define NEG_SLOPE 0.2f

typedef _Float16 f16x8 __attribute__((ext_vector_type(8)));
typedef float f32x4 __attribute__((ext_vector_type(4)));

// ================= prologue kernels =================

// deg atomics | bsum[l][f]=sum_h bias | WABall[l][k][j] = sum_f W[l][k][h*64+f]*a[h][f]
__global__ __launch_bounds__(256) void k_pro(
        const int* __restrict__ dst, int* __restrict__ deg,
        const float* __restrict__ W, const float* __restrict__ al,
        const float* __restrict__ ar, const float* __restrict__ bias,
        float* __restrict__ bsum, float* __restrict__ WABall, int ne) {
    int i = blockIdx.x * blockDim.x + threadIdx.x;
    if (i < ne) { atomicAdd(&deg[dst[i]], 1); return; }
    int j = i - ne;
    if (j < 256) {
        int l = j >> 6, f = j & 63;
        float s = 0.f;
        #pragma unroll
        for (int h = 0; h < 4; ++h) s += bias[(l << 8) + h * 64 + f];
        bsum[j] = s;
        return;
    }
    int j2 = j - 256;
    if (j2 < 2048) {                      // WABall, flat ((l*64+k)*8+jj)
        int l = j2 >> 9, r = j2 & 511, k = r >> 3, jj = r & 7, hh = jj & 3;
        const float* wrow = W + (l << 14) + (k << 8) + hh * 64;
        const float* av = ((jj < 4) ? al : ar) + (l << 8) + hh * 64;
        float s = 0.f;
        #pragma unroll 8
        for (int f = 0; f < 64; ++f) s = fmaf(wrow[f], av[f], s);
        WABall[j2] = s;
    }
}

// Pack transform B-frags | WABf0 frags | cl consts
__global__ __launch_bounds__(256) void k_packT(
        const float* __restrict__ W, const float* __restrict__ WABall,
        const float* __restrict__ bsum,
        _Float16* __restrict__ Bf, _Float16* __restrict__ WABf0,
        float* __restrict__ cl) {
    int i = blockIdx.x * blockDim.x + threadIdx.x;
    if (i < 4 * 20480) {
        int l = i / 20480, r = i % 20480;
        int j = r & 7, lane = (r >> 3) & 63, kc = (r >> 9) & 7, ct = r >> 12;
        int k = kc * 32 + ((lane >> 4) << 3) + j;
        int c = ct * 16 + (lane & 15);
        int fi = k & 63, hh = k >> 6;
        float v = 0.f;
        if (c < 64) {
            v = W[(l << 14) + (fi << 8) + hh * 64 + c];
        } else if (c < 72 && l < 3) {
            int jj = c - 64;
            const float* wr = W + (l << 14) + (fi << 8) + hh * 64;
            const float* wa = WABall + (((l + 1) * 64) << 3) + jj;
            float s = 0.f;
            #pragma unroll 8
            for (int fo = 0; fo < 64; ++fo) s = fmaf(wr[fo], wa[fo << 3], s);
            v = s;
        }
        Bf[i] = (_Float16)v;
        return;
    }
    int i2 = i - 4 * 20480;
    if (i2 < 1024) {
        int j = i2 & 7, lane = (i2 >> 3) & 63, kc = i2 >> 9;
        int k = kc * 32 + ((lane >> 4) << 3) + j;
        int col = lane & 15;
        float v = (col < 8) ? WABall[(k << 3) + col] : 0.f;
        WABf0[i2] = (_Float16)v;
        return;
    }
    int i3 = i2 - 1024;
    if (i3 < 24) {
        int l = i3 >> 3, jj = i3 & 7;
        const float* wa = WABall + (((l + 1) * 64) << 3) + jj;
        float s = 0.f;
        #pragma unroll 8
        for (int fo = 0; fo < 64; ++fo) s = fmaf(bsum[l * 64 + fo], wa[fo << 3], s);
        cl[l * 8 + jj] = s;
    }
}

#define SCB 2048
__global__ __launch_bounds__(256) void k_scan1(const int* __restrict__ deg,
                                               int* __restrict__ bsums, int n) {
    __shared__ int wsum[4];
    int b = blockIdx.x, t = threadIdx.x;
    int i0 = b * SCB + t * 8;
    int s = 0;
    #pragma unroll
    for (int j = 0; j < 8; ++j) { int i = i0 + j; if (i < n) s += deg[i]; }
    #pragma unroll
    for (int m = 1; m < 64; m <<= 1) s += __shfl_xor(s, m);
    if ((t & 63) == 0) wsum[t >> 6] = s;
    __syncthreads();
    if (t == 0) bsums[b] = wsum[0] + wsum[1] + wsum[2] + wsum[3];
}

__global__ __launch_bounds__(256) void k_scan23(const int* __restrict__ deg,
                                                const int* __restrict__ bsums,
                                                int* __restrict__ rowptr,
                                                int* __restrict__ cursor,
                                                int n, int nb) {
    __shared__ int woff[4];
    __shared__ int boffs;
    int b = blockIdx.x, t = threadIdx.x, lane = t & 63, w = t >> 6;
    if (t < 64) {
        int v = (lane < nb) ? bsums[lane] : 0;
        int s = v;
        #pragma unroll
        for (int m = 1; m < 64; m <<= 1) {
            int y = __shfl_up(s, m);
            if (lane >= m) s += y;
        }
        if (lane == b) boffs = s - v;
        if (b == 0 && lane == nb - 1) rowptr[n] = s;
    }
    __syncthreads();
    int i0 = b * SCB + t * 8;
    int v[8]; int s8 = 0;
    #pragma unroll
    for (int j = 0; j < 8; ++j) { int i = i0 + j; v[j] = (i < n) ? deg[i] : 0; s8 += v[j]; }
    int s = s8;
    #pragma unroll
    for (int m = 1; m < 64; m <<= 1) { int y = __shfl_up(s, m); if (lane >= m) s += y; }
    if (lane == 63) woff[w] = s;
    __syncthreads();
    int wo = 0;
    #pragma unroll
    for (int k = 0; k < 4; ++k) if (k < w) wo += woff[k];
    int excl = boffs + wo + s - s8;
    #pragma unroll
    for (int j = 0; j < 8; ++j) {
        int i = i0 + j;
        if (i < n) { rowptr[i] = excl; cursor[i] = excl; }
        excl += v[j];
    }
}

__global__ __launch_bounds__(256) void k_scatter(const int* __restrict__ src,
                                                 const int* __restrict__ dst,
                                                 int* __restrict__ cursor,
                                                 int* __restrict__ csr_src, int ne) {
    int e = blockIdx.x * blockDim.x + threadIdx.x;
    if (e >= ne) return;
    int pos = atomicAdd(&cursor[dst[e]], 1);
    csr_src[pos] = src[e];
}

// ================= layer kernels =================

// k0: x16 = (f16)feat, el/er_0 = feat . WAB_0 via 2 MFMA
__global__ __launch_bounds__(256) void k0(
        const float* __restrict__ feat, const _Float16* __restrict__ WABf0,
        _Float16* __restrict__ x16, float* __restrict__ el, float* __restrict__ er,
        int n) {
    int t = threadIdx.x, w = t >> 6, lane = t & 63;
    int r0 = blockIdx.x * 64 + w * 16;
    if (r0 >= n) return;
    int m = lane & 15, kb = lane >> 4;
    int gr = r0 + m;

    f16x8 A0, A1;
    if (gr < n) {
        const float* hp = feat + (size_t)gr * 64 + kb * 8;
        float4 p0 = *(const float4*)(hp);
        float4 p1 = *(const float4*)(hp + 4);
        float4 q0 = *(const float4*)(hp + 32);
        float4 q1 = *(const float4*)(hp + 36);
        A0[0] = (_Float16)p0.x; A0[1] = (_Float16)p0.y;
        A0[2] = (_Float16)p0.z; A0[3] = (_Float16)p0.w;
        A0[4] = (_Float16)p1.x; A0[5] = (_Float16)p1.y;
        A0[6] = (_Float16)p1.z; A0[7] = (_Float16)p1.w;
        A1[0] = (_Float16)q0.x; A1[1] = (_Float16)q0.y;
        A1[2] = (_Float16)q0.z; A1[3] = (_Float16)q0.w;
        A1[4] = (_Float16)q1.x; A1[5] = (_Float16)q1.y;
        A1[6] = (_Float16)q1.z; A1[7] = (_Float16)q1.w;
    } else {
        #pragma unroll
        for (int j = 0; j < 8; ++j) { A0[j] = (_Float16)0.f; A1[j] = (_Float16)0.f; }
    }

    {
        f16x8 wb0 = *(const f16x8*)(WABf0 + lane * 8);
        f16x8 wb1 = *(const f16x8*)(WABf0 + 512 + lane * 8);
        f32x4 e; e[0] = 0.f; e[1] = 0.f; e[2] = 0.f; e[3] = 0.f;
        e = __builtin_amdgcn_mfma_f32_16x16x32_f16(A0, wb0, e, 0, 0, 0);
        e = __builtin_amdgcn_mfma_f32_16x16x32_f16(A1, wb1, e, 0, 0, 0);
        if (m < 8) {
            float* dp = (m < 4) ? el : er;
            #pragma unroll
            for (int r = 0; r < 4; ++r) {
                int g2 = r0 + kb * 4 + r;
                if (g2 < n) dp[(size_t)g2 * 4 + (m & 3)] = e[r];
            }
        }
    }

    if (gr < n) {
        *(f16x8*)(x16 + (size_t)gr * 64 + kb * 8) = A0;
        *(f16x8*)(x16 + (size_t)gr * 64 + 32 + kb * 8) = A1;
    }
}

// k_layer: FUSED aggregation + transform. Block = 4 waves = 16 dst nodes
// (wave w -> nodes r0+w*4+{0..3}, serially). Aggregation writes agg rows to
// LDS tile at[16][272] (f16); after syncthreads each wave runs one ct-tile
// of the MFMA transform (wave 3 also ct=4 -> next-layer el/er).
// Reads epoch-in {x16i, eli, eri}; writes epoch-out {x16o, elo, ero} / outF.
__global__ __launch_bounds__(256) void k_layer(
        const int* __restrict__ rowptr, const int* __restrict__ csr_src,
        const float* __restrict__ eli, const float* __restrict__ eri,
        const _Float16* __restrict__ x16i, const _Float16* __restrict__ Bf,
        const float* __restrict__ bsum, const float* __restrict__ cl,
        _Float16* __restrict__ x16o, float* __restrict__ elo,
        float* __restrict__ ero, float* __restrict__ outF, int n, int last) {
    __shared__ float lds_ee[4][96];
    __shared__ int   lds_s[4][24];
    __shared__ _Float16 at[16 * 272];
    int t = threadIdx.x, w = t >> 6, lane = t & 63;
    int r0 = blockIdx.x * 16;
    int ei = lane >> 2, hh = lane & 3;
    int q = lane & 31, half = lane >> 5;

    if (lane < 32) lds_ee[w][64 + lane] = 0.f;   // pad ee slots, once

    // ---- aggregation: 4 nodes per wave, serial ----
    for (int j = 0; j < 4; ++j) {
        int d = r0 + w * 4 + j;
        _Float16* atr = at + (w * 4 + j) * 272;
        int rbeg = 0, rend = 0;
        if (d < n) { rbeg = rowptr[d]; rend = rowptr[d + 1]; }
        if (rend == rbeg) {
            if (half == 0) {
                __half2 z = __floats2half2_rn(0.f, 0.f);
                *(__half2*)(atr + q * 2)       = z;
                *(__half2*)(atr + 64 + q * 2)  = z;
                *(__half2*)(atr + 128 + q * 2) = z;
                *(__half2*)(atr + 192 + q * 2) = z;
            }
            continue;
        }
        float erh = eri[(size_t)d * 4 + hh];

        int idx0 = rbeg + ei;
        bool v0 = idx0 < rend;
        int s0 = v0 ? csr_src[idx0] : 0;
        int sfb = __shfl(s0, 0);
        if (lane < 8) lds_s[w][16 + lane] = sfb;   // pad src slots, per node

        float ee0 = 0.f;
        if (v0) {
            float x = eli[(size_t)s0 * 4 + hh] + erh;
            x = x > 0.f ? x : NEG_SLOPE * x;
            ee0 = __expf(x);
        }
        float dsum = ee0;
        float2 acc[4];
        #pragma unroll
        for (int h = 0; h < 4; ++h) acc[h] = make_float2(0.f, 0.f);
        lds_ee[w][lane] = ee0;
        if (hh == 0) lds_s[w][ei] = v0 ? s0 : sfb;
        {
            int csz = min(16, rend - rbeg);
            int np = (csz + 1) >> 1;
            for (int p0 = 0; p0 < np; p0 += 2) {
                #pragma unroll
                for (int jj = 0; jj < 2; ++jj) {
                    int i = 2 * (p0 + jj) + half;
                    float4 ee4 = *(float4*)&lds_ee[w][i * 4];
                    int s = lds_s[w][i];
                    unsigned u = *(const unsigned*)(x16i + (size_t)s * 64 + q * 2);
                    float2 xv = __half22float2(*(__half2*)&u);
                    acc[0].x += ee4.x * xv.x; acc[0].y += ee4.x * xv.y;
                    acc[1].x += ee4.y * xv.x; acc[1].y += ee4.y * xv.y;
                    acc[2].x += ee4.z * xv.x; acc[2].y += ee4.z * xv.y;
                    acc[3].x += ee4.w * xv.x; acc[3].y += ee4.w * xv.y;
                }
            }
        }
        for (int base = rbeg + 16; base < rend; base += 16) {
            int idx = base + ei;
            int e16 = min(16, rend - base);
            float ee = 0.f;
            if (idx < rend) {
                int s = csr_src[idx];
                float x = eli[(size_t)s * 4 + hh] + erh;
                x = x > 0.f ? x : NEG_SLOPE * x;
                ee = __expf(x);
                if (hh == 0) lds_s[w][ei] = s;
            }
            dsum += ee;
            lds_ee[w][lane] = ee;
            int np = (e16 + 1) >> 1;
            for (int p0 = 0; p0 < np; p0 += 2) {
                #pragma unroll
                for (int jj = 0; jj < 2; ++jj) {
                    int i = 2 * (p0 + jj) + half;
                    float4 ee4 = *(float4*)&lds_ee[w][i * 4];
                    int s = lds_s[w][i];
                    unsigned u = *(const unsigned*)(x16i + (size_t)s * 64 + q * 2);
                    float2 xv = __half22float2(*(__half2*)&u);
                    acc[0].x += ee4.x * xv.x; acc[0].y += ee4.x * xv.y;
                    acc[1].x += ee4.y * xv.x; acc[1].y += ee4.y * xv.y;
                    acc[2].x += ee4.z * xv.x; acc[2].y += ee4.z * xv.y;
                    acc[3].x += ee4.w * xv.x; acc[3].y += ee4.w * xv.y;
                }
            }
        }
        #pragma unroll
        for (int msk = 4; msk < 64; msk <<= 1) dsum += __shfl_xor(dsum, msk);
        float dh0 = __shfl(dsum, 0), dh1 = __shfl(dsum, 1);
        float dh2 = __shfl(dsum, 2), dh3 = __shfl(dsum, 3);
        #pragma unroll
        for (int h = 0; h < 4; ++h) {
            acc[h].x += __shfl_xor(acc[h].x, 32);
            acc[h].y += __shfl_xor(acc[h].y, 32);
        }
        if (half == 0) {
            float rd0 = 1.f / dh0, rd1 = 1.f / dh1, rd2 = 1.f / dh2, rd3 = 1.f / dh3;
            *(__half2*)(atr + q * 2)       = __floats2half2_rn(acc[0].x * rd0, acc[0].y * rd0);
            *(__half2*)(atr + 64 + q * 2)  = __floats2half2_rn(acc[1].x * rd1, acc[1].y * rd1);
            *(__half2*)(atr + 128 + q * 2) = __floats2half2_rn(acc[2].x * rd2, acc[2].y * rd2);
            *(__half2*)(atr + 192 + q * 2) = __floats2half2_rn(acc[3].x * rd3, acc[3].y * rd3);
        }
    }
    __syncthreads();

    // ---- transform: A-frags from LDS, wave w -> ct=w (wave 3 also ct=4) ----
    int m = lane & 15, kb = lane >> 4;
    f16x8 A[8];
    #pragma unroll
    for (int kc = 0; kc < 8; ++kc)
        A[kc] = *(const f16x8*)&at[m * 272 + kc * 32 + kb * 8];

    {
        int ct = w;
        f32x4 dd; dd[0] = 0.f; dd[1] = 0.f; dd[2] = 0.f; dd[3] = 0.f;
        #pragma unroll
        for (int kc = 0; kc < 8; ++kc) {
            f16x8 b = *(const f16x8*)(Bf + ((ct * 8 + kc) * 64 + lane) * 8);
            dd = __builtin_amdgcn_mfma_f32_16x16x32_f16(A[kc], b, dd, 0, 0, 0);
        }
        int col = ct * 16 + m;
        float bv = bsum[col];
        #pragma unroll
        for (int r = 0; r < 4; ++r) {
            int g2 = r0 + kb * 4 + r;
            if (g2 < n) {
                if (last) outF[(size_t)g2 * 64 + col] = dd[r] + bv;
                else      x16o[(size_t)g2 * 64 + col] = (_Float16)(dd[r] + bv);
            }
        }
    }
    if (w == 3 && !last) {
        f32x4 dd; dd[0] = 0.f; dd[1] = 0.f; dd[2] = 0.f; dd[3] = 0.f;
        #pragma unroll
        for (int kc = 0; kc < 8; ++kc) {
            f16x8 b = *(const f16x8*)(Bf + ((32 + kc) * 64 + lane) * 8);
            dd = __builtin_amdgcn_mfma_f32_16x16x32_f16(A[kc], b, dd, 0, 0, 0);
        }
        if (m < 8) {
            float cv = cl[m];
            float* dp = (m < 4) ? elo : ero;
            #pragma unroll
            for (int r = 0; r < 4; ++r) {
                int g2 = r0 + kb * 4 + r;
                if (g2 < n) dp[(size_t)g2 * 4 + (m & 3)] = dd[r] + cv;
            }
        }
    }
}

// ================= launcher =================

extern "C" void kernel_launch(void* const* d_in, const int* in_sizes, int n_in,
                              void* d_out, int out_size, void* d_ws, size_t ws_size,
                              hipStream_t stream) {
    const float* feat = (const float*)d_in[0];
    const float* W    = (const float*)d_in[1];
    const float* al   = (const float*)d_in[2];
    const float* ar   = (const float*)d_in[3];
    const float* bias = (const float*)d_in[4];
    const int*   src  = (const int*)d_in[5];
    const int*   dst  = (const int*)d_in[6];
    float* out = (float*)d_out;

    const int N = in_sizes[0] / 64;   // 50000
    const int E = in_sizes[5];        // 500000
    const int L = 4;

    // workspace carve (float units)
    float* ws = (float*)d_ws;
    _Float16* x16A = (_Float16*)ws;                        // N*64 halves
    _Float16* x16B = (_Float16*)(ws + (size_t)N * 32);     // N*64 halves
    float* elA    = ws + (size_t)N * 64;                   // N*4
    float* erA    = elA + (size_t)N * 4;                   // N*4
    float* elB    = erA + (size_t)N * 4;                   // N*4
    float* erB    = elB + (size_t)N * 4;                   // N*4
    float* bsum   = erB + (size_t)N * 4;                   // 256
    float* WABall = bsum + 256;                            // 2048
    float* cl     = WABall + 2048;                         // 32
    _Float16* Bf    = (_Float16*)(cl + 32);                // 4*20480 halves
    _Float16* WABf0 = (_Float16*)((float*)Bf + 40960);     // 1024 halves
    int* rowptr  = (int*)((float*)WABf0 + 512);            // N+1
    int* cursor  = rowptr + (N + 1);                       // N
    int* deg     = cursor + N;                             // N
    int* csr_src = deg + N;                                // E
    int* bsums   = csr_src + E;                            // 32

    const int NB = (N + SCB - 1) / SCB;                    // 25

    // ---- prologue ----
    hipMemsetAsync(deg, 0, (size_t)N * sizeof(int), stream);
    int pro_total = E + 256 + 2048;
    k_pro<<<(pro_total + 255) / 256, 256, 0, stream>>>(
        dst, deg, W, al, ar, bias, bsum, WABall, E);
    k_packT<<<(4 * 20480 + 1024 + 24 + 255) / 256, 256, 0, stream>>>(
        W, WABall, bsum, Bf, WABf0, cl);
    k_scan1<<<NB, 256, 0, stream>>>(deg, bsums, N);
    k_scan23<<<NB, 256, 0, stream>>>(deg, bsums, rowptr, cursor, N, NB);
    k_scatter<<<(E + 255) / 256, 256, 0, stream>>>(src, dst, cursor, csr_src, E);

    // ---- layer 0 input (epoch A) ----
    k0<<<(N + 63) / 64, 256, 0, stream>>>(feat, WABf0, x16A, elA, erA, N);

    // ---- layers: fused aggregation + transform, ping-pong epochs ----
    _Float16* xin = x16A; float* eli = elA; float* eri = erA;
    _Float16* xot = x16B; float* elo = elB; float* ero = erB;
    for (int l = 0; l < L; ++l) {
        int last = (l == L - 1);
        k_layer<<<(N + 15) / 16, 256, 0, stream>>>(
            rowptr, csr_src, eli, eri, xin,
            Bf + (size_t)l * 20480, bsum + (size_t)l * 64,
            cl + (size_t)(l < 3 ? l : 0) * 8,
            xot, elo, ero, out, N, last);
        _Float16* tx = xin; xin = xot; xot = tx;
        float* te = eli; eli = elo; elo = te;
        te = eri; eri = ero; ero = te;
    }
}

// Round 15
// 230.562 us; speedup vs baseline: 1.0682x; 1.0077x over previous
//
#include <hip/hip_runtime.h>
#include <hip/hip_fp16.h>

#define NEG_SLOPE 0.2f

typedef _Float16 f16x8 __attribute__((ext_vector_type(8)));
typedef float f32x4 __attribute__((ext_vector_type(4)));

// ================= prologue kernels =================

// deg atomics | bsum[l][f]=sum_h bias | WABall[l][k][j] = sum_f W[l][k][h*64+f]*a[h][f]
__global__ __launch_bounds__(256) void k_pro(
        const int* __restrict__ dst, int* __restrict__ deg,
        const float* __restrict__ W, const float* __restrict__ al,
        const float* __restrict__ ar, const float* __restrict__ bias,
        float* __restrict__ bsum, float* __restrict__ WABall, int ne) {
    int i = blockIdx.x * blockDim.x + threadIdx.x;
    if (i < ne) { atomicAdd(&deg[dst[i]], 1); return; }
    int j = i - ne;
    if (j < 256) {
        int l = j >> 6, f = j & 63;
        float s = 0.f;
        #pragma unroll
        for (int h = 0; h < 4; ++h) s += bias[(l << 8) + h * 64 + f];
        bsum[j] = s;
        return;
    }
    int j2 = j - 256;
    if (j2 < 2048) {                      // WABall, flat ((l*64+k)*8+jj)
        int l = j2 >> 9, r = j2 & 511, k = r >> 3, jj = r & 7, hh = jj & 3;
        const float* wrow = W + (l << 14) + (k << 8) + hh * 64;
        const float* av = ((jj < 4) ? al : ar) + (l << 8) + hh * 64;
        float s = 0.f;
        #pragma unroll 8
        for (int f = 0; f < 64; ++f) s = fmaf(wrow[f], av[f], s);
        WABall[j2] = s;
    }
}

// Pack transform B-frags | WABf0 frags | cl consts
__global__ __launch_bounds__(256) void k_packT(
        const float* __restrict__ W, const float* __restrict__ WABall,
        const float* __restrict__ bsum,
        _Float16* __restrict__ Bf, _Float16* __restrict__ WABf0,
        float* __restrict__ cl) {
    int i = blockIdx.x * blockDim.x + threadIdx.x;
    if (i < 4 * 20480) {
        int l = i / 20480, r = i % 20480;
        int j = r & 7, lane = (r >> 3) & 63, kc = (r >> 9) & 7, ct = r >> 12;
        int k = kc * 32 + ((lane >> 4) << 3) + j;
        int c = ct * 16 + (lane & 15);
        int fi = k & 63, hh = k >> 6;
        float v = 0.f;
        if (c < 64) {
            v = W[(l << 14) + (fi << 8) + hh * 64 + c];
        } else if (c < 72 && l < 3) {
            int jj = c - 64;
            const float* wr = W + (l << 14) + (fi << 8) + hh * 64;
            const float* wa = WABall + (((l + 1) * 64) << 3) + jj;
            float s = 0.f;
            #pragma unroll 8
            for (int fo = 0; fo < 64; ++fo) s = fmaf(wr[fo], wa[fo << 3], s);
            v = s;
        }
        Bf[i] = (_Float16)v;
        return;
    }
    int i2 = i - 4 * 20480;
    if (i2 < 1024) {
        int j = i2 & 7, lane = (i2 >> 3) & 63, kc = i2 >> 9;
        int k = kc * 32 + ((lane >> 4) << 3) + j;
        int col = lane & 15;
        float v = (col < 8) ? WABall[(k << 3) + col] : 0.f;
        WABf0[i2] = (_Float16)v;
        return;
    }
    int i3 = i2 - 1024;
    if (i3 < 24) {
        int l = i3 >> 3, jj = i3 & 7;
        const float* wa = WABall + (((l + 1) * 64) << 3) + jj;
        float s = 0.f;
        #pragma unroll 8
        for (int fo = 0; fo < 64; ++fo) s = fmaf(bsum[l * 64 + fo], wa[fo << 3], s);
        cl[l * 8 + jj] = s;
    }
}

#define SCB 2048
__global__ __launch_bounds__(256) void k_scan1(const int* __restrict__ deg,
                                               int* __restrict__ bsums, int n) {
    __shared__ int wsum[4];
    int b = blockIdx.x, t = threadIdx.x;
    int i0 = b * SCB + t * 8;
    int s = 0;
    #pragma unroll
    for (int j = 0; j < 8; ++j) { int i = i0 + j; if (i < n) s += deg[i]; }
    #pragma unroll
    for (int m = 1; m < 64; m <<= 1) s += __shfl_xor(s, m);
    if ((t & 63) == 0) wsum[t >> 6] = s;
    __syncthreads();
    if (t == 0) bsums[b] = wsum[0] + wsum[1] + wsum[2] + wsum[3];
}

__global__ __launch_bounds__(256) void k_scan23(const int* __restrict__ deg,
                                                const int* __restrict__ bsums,
                                                int* __restrict__ rowptr,
                                                int* __restrict__ cursor,
                                                int n, int nb) {
    __shared__ int woff[4];
    __shared__ int boffs;
    int b = blockIdx.x, t = threadIdx.x, lane = t & 63, w = t >> 6;
    if (t < 64) {
        int v = (lane < nb) ? bsums[lane] : 0;
        int s = v;
        #pragma unroll
        for (int m = 1; m < 64; m <<= 1) {
            int y = __shfl_up(s, m);
            if (lane >= m) s += y;
        }
        if (lane == b) boffs = s - v;
        if (b == 0 && lane == nb - 1) rowptr[n] = s;
    }
    __syncthreads();
    int i0 = b * SCB + t * 8;
    int v[8]; int s8 = 0;
    #pragma unroll
    for (int j = 0; j < 8; ++j) { int i = i0 + j; v[j] = (i < n) ? deg[i] : 0; s8 += v[j]; }
    int s = s8;
    #pragma unroll
    for (int m = 1; m < 64; m <<= 1) { int y = __shfl_up(s, m); if (lane >= m) s += y; }
    if (lane == 63) woff[w] = s;
    __syncthreads();
    int wo = 0;
    #pragma unroll
    for (int k = 0; k < 4; ++k) if (k < w) wo += woff[k];
    int excl = boffs + wo + s - s8;
    #pragma unroll
    for (int j = 0; j < 8; ++j) {
        int i = i0 + j;
        if (i < n) { rowptr[i] = excl; cursor[i] = excl; }
        excl += v[j];
    }
}

__global__ __launch_bounds__(256) void k_scatter(const int* __restrict__ src,
                                                 const int* __restrict__ dst,
                                                 int* __restrict__ cursor,
                                                 int* __restrict__ csr_src, int ne) {
    int e = blockIdx.x * blockDim.x + threadIdx.x;
    if (e >= ne) return;
    int pos = atomicAdd(&cursor[dst[e]], 1);
    csr_src[pos] = src[e];
}

// ================= layer kernels =================

// k0: x16 = (f16)feat, el/er_0 = feat . WAB_0 via 2 MFMA
__global__ __launch_bounds__(256) void k0(
        const float* __restrict__ feat, const _Float16* __restrict__ WABf0,
        _Float16* __restrict__ x16, float* __restrict__ el, float* __restrict__ er,
        int n) {
    int t = threadIdx.x, w = t >> 6, lane = t & 63;
    int r0 = blockIdx.x * 64 + w * 16;
    if (r0 >= n) return;
    int m = lane & 15, kb = lane >> 4;
    int gr = r0 + m;

    f16x8 A0, A1;
    if (gr < n) {
        const float* hp = feat + (size_t)gr * 64 + kb * 8;
        float4 p0 = *(const float4*)(hp);
        float4 p1 = *(const float4*)(hp + 4);
        float4 q0 = *(const float4*)(hp + 32);
        float4 q1 = *(const float4*)(hp + 36);
        A0[0] = (_Float16)p0.x; A0[1] = (_Float16)p0.y;
        A0[2] = (_Float16)p0.z; A0[3] = (_Float16)p0.w;
        A0[4] = (_Float16)p1.x; A0[5] = (_Float16)p1.y;
        A0[6] = (_Float16)p1.z; A0[7] = (_Float16)p1.w;
        A1[0] = (_Float16)q0.x; A1[1] = (_Float16)q0.y;
        A1[2] = (_Float16)q0.z; A1[3] = (_Float16)q0.w;
        A1[4] = (_Float16)q1.x; A1[5] = (_Float16)q1.y;
        A1[6] = (_Float16)q1.z; A1[7] = (_Float16)q1.w;
    } else {
        #pragma unroll
        for (int j = 0; j < 8; ++j) { A0[j] = (_Float16)0.f; A1[j] = (_Float16)0.f; }
    }

    {
        f16x8 wb0 = *(const f16x8*)(WABf0 + lane * 8);
        f16x8 wb1 = *(const f16x8*)(WABf0 + 512 + lane * 8);
        f32x4 e; e[0] = 0.f; e[1] = 0.f; e[2] = 0.f; e[3] = 0.f;
        e = __builtin_amdgcn_mfma_f32_16x16x32_f16(A0, wb0, e, 0, 0, 0);
        e = __builtin_amdgcn_mfma_f32_16x16x32_f16(A1, wb1, e, 0, 0, 0);
        if (m < 8) {
            float* dp = (m < 4) ? el : er;
            #pragma unroll
            for (int r = 0; r < 4; ++r) {
                int g2 = r0 + kb * 4 + r;
                if (g2 < n) dp[(size_t)g2 * 4 + (m & 3)] = e[r];
            }
        }
    }

    if (gr < n) {
        *(f16x8*)(x16 + (size_t)gr * 64 + kb * 8) = A0;
        *(f16x8*)(x16 + (size_t)gr * 64 + 32 + kb * 8) = A1;
    }
}

// k_layer: FUSED aggregation + transform, with node-setup software pipelining:
// all 4 nodes' independent setup loads (rowptr, csr_src chunk0, el, er, exp)
// are hoisted and issued up front; the LDS-serialized gather/reduce phases
// then run per node with setup latency already absorbed.
__global__ __launch_bounds__(256) void k_layer(
        const int* __restrict__ rowptr, const int* __restrict__ csr_src,
        const float* __restrict__ eli, const float* __restrict__ eri,
        const _Float16* __restrict__ x16i, const _Float16* __restrict__ Bf,
        const float* __restrict__ bsum, const float* __restrict__ cl,
        _Float16* __restrict__ x16o, float* __restrict__ elo,
        float* __restrict__ ero, float* __restrict__ outF, int n, int last) {
    __shared__ float lds_ee[4][96];
    __shared__ int   lds_s[4][24];
    __shared__ _Float16 at[16 * 272];
    int t = threadIdx.x, w = t >> 6, lane = t & 63;
    int r0 = blockIdx.x * 16;
    int ei = lane >> 2, hh = lane & 3;
    int q = lane & 31, half = lane >> 5;

    if (lane < 32) lds_ee[w][64 + lane] = 0.f;   // pad ee slots, once

    // ---- setup phase: all 4 nodes, independent loads issued together ----
    int rbegA[4], rendA[4], s0A[4];
    float ee0A[4], erhA[4];
    bool v0A[4];
    #pragma unroll
    for (int j = 0; j < 4; ++j) {
        int d = r0 + w * 4 + j;
        int rb = 0, re = 0;
        if (d < n) { rb = rowptr[d]; re = rowptr[d + 1]; }
        rbegA[j] = rb; rendA[j] = re;
        erhA[j] = (d < n && re > rb) ? eri[(size_t)d * 4 + hh] : 0.f;
    }
    #pragma unroll
    for (int j = 0; j < 4; ++j) {
        int idx0 = rbegA[j] + ei;
        bool v0 = (idx0 < rendA[j]) && (rendA[j] > rbegA[j]);
        v0A[j] = v0;
        s0A[j] = v0 ? csr_src[idx0] : 0;
    }
    #pragma unroll
    for (int j = 0; j < 4; ++j) {
        float ee = 0.f;
        if (v0A[j]) {
            float x = eli[(size_t)s0A[j] * 4 + hh] + erhA[j];
            x = x > 0.f ? x : NEG_SLOPE * x;
            ee = __expf(x);
        }
        ee0A[j] = ee;
    }

    // ---- per-node gather/reduce (LDS slots reused serially) ----
    for (int j = 0; j < 4; ++j) {
        int d = r0 + w * 4 + j;
        _Float16* atr = at + (w * 4 + j) * 272;
        int rbeg = rbegA[j], rend = rendA[j];
        if (rend == rbeg) {
            if (half == 0) {
                __half2 z = __floats2half2_rn(0.f, 0.f);
                *(__half2*)(atr + q * 2)       = z;
                *(__half2*)(atr + 64 + q * 2)  = z;
                *(__half2*)(atr + 128 + q * 2) = z;
                *(__half2*)(atr + 192 + q * 2) = z;
            }
            continue;
        }
        bool v0 = v0A[j];
        int s0 = s0A[j];
        int sfb = __shfl(s0, 0);
        if (lane < 8) lds_s[w][16 + lane] = sfb;   // pad src slots, per node

        float ee0 = ee0A[j];
        float dsum = ee0;
        float2 acc[4];
        #pragma unroll
        for (int h = 0; h < 4; ++h) acc[h] = make_float2(0.f, 0.f);
        lds_ee[w][lane] = ee0;
        if (hh == 0) lds_s[w][ei] = v0 ? s0 : sfb;
        {
            int csz = min(16, rend - rbeg);
            int np = (csz + 1) >> 1;
            for (int p0 = 0; p0 < np; p0 += 2) {
                #pragma unroll
                for (int jj = 0; jj < 2; ++jj) {
                    int i = 2 * (p0 + jj) + half;
                    float4 ee4 = *(float4*)&lds_ee[w][i * 4];
                    int s = lds_s[w][i];
                    unsigned u = *(const unsigned*)(x16i + (size_t)s * 64 + q * 2);
                    float2 xv = __half22float2(*(__half2*)&u);
                    acc[0].x += ee4.x * xv.x; acc[0].y += ee4.x * xv.y;
                    acc[1].x += ee4.y * xv.x; acc[1].y += ee4.y * xv.y;
                    acc[2].x += ee4.z * xv.x; acc[2].y += ee4.z * xv.y;
                    acc[3].x += ee4.w * xv.x; acc[3].y += ee4.w * xv.y;
                }
            }
        }
        for (int base = rbeg + 16; base < rend; base += 16) {
            int idx = base + ei;
            int e16 = min(16, rend - base);
            float ee = 0.f;
            if (idx < rend) {
                int s = csr_src[idx];
                float x = eli[(size_t)s * 4 + hh] + erhA[j];
                x = x > 0.f ? x : NEG_SLOPE * x;
                ee = __expf(x);
                if (hh == 0) lds_s[w][ei] = s;
            }
            dsum += ee;
            lds_ee[w][lane] = ee;
            int np = (e16 + 1) >> 1;
            for (int p0 = 0; p0 < np; p0 += 2) {
                #pragma unroll
                for (int jj = 0; jj < 2; ++jj) {
                    int i = 2 * (p0 + jj) + half;
                    float4 ee4 = *(float4*)&lds_ee[w][i * 4];
                    int s = lds_s[w][i];
                    unsigned u = *(const unsigned*)(x16i + (size_t)s * 64 + q * 2);
                    float2 xv = __half22float2(*(__half2*)&u);
                    acc[0].x += ee4.x * xv.x; acc[0].y += ee4.x * xv.y;
                    acc[1].x += ee4.y * xv.x; acc[1].y += ee4.y * xv.y;
                    acc[2].x += ee4.z * xv.x; acc[2].y += ee4.z * xv.y;
                    acc[3].x += ee4.w * xv.x; acc[3].y += ee4.w * xv.y;
                }
            }
        }
        #pragma unroll
        for (int msk = 4; msk < 64; msk <<= 1) dsum += __shfl_xor(dsum, msk);
        float dh0 = __shfl(dsum, 0), dh1 = __shfl(dsum, 1);
        float dh2 = __shfl(dsum, 2), dh3 = __shfl(dsum, 3);
        #pragma unroll
        for (int h = 0; h < 4; ++h) {
            acc[h].x += __shfl_xor(acc[h].x, 32);
            acc[h].y += __shfl_xor(acc[h].y, 32);
        }
        if (half == 0) {
            float rd0 = 1.f / dh0, rd1 = 1.f / dh1, rd2 = 1.f / dh2, rd3 = 1.f / dh3;
            *(__half2*)(atr + q * 2)       = __floats2half2_rn(acc[0].x * rd0, acc[0].y * rd0);
            *(__half2*)(atr + 64 + q * 2)  = __floats2half2_rn(acc[1].x * rd1, acc[1].y * rd1);
            *(__half2*)(atr + 128 + q * 2) = __floats2half2_rn(acc[2].x * rd2, acc[2].y * rd2);
            *(__half2*)(atr + 192 + q * 2) = __floats2half2_rn(acc[3].x * rd3, acc[3].y * rd3);
        }
    }
    __syncthreads();

    // ---- transform: A-frags from LDS, wave w -> ct=w (wave 3 also ct=4) ----
    int m = lane & 15, kb = lane >> 4;
    f16x8 A[8];
    #pragma unroll
    for (int kc = 0; kc < 8; ++kc)
        A[kc] = *(const f16x8*)&at[m * 272 + kc * 32 + kb * 8];

    {
        int ct = w;
        f32x4 dd; dd[0] = 0.f; dd[1] = 0.f; dd[2] = 0.f; dd[3] = 0.f;
        #pragma unroll
        for (int kc = 0; kc < 8; ++kc) {
            f16x8 b = *(const f16x8*)(Bf + ((ct * 8 + kc) * 64 + lane) * 8);
            dd = __builtin_amdgcn_mfma_f32_16x16x32_f16(A[kc], b, dd, 0, 0, 0);
        }
        int col = ct * 16 + m;
        float bv = bsum[col];
        #pragma unroll
        for (int r = 0; r < 4; ++r) {
            int g2 = r0 + kb * 4 + r;
            if (g2 < n) {
                if (last) outF[(size_t)g2 * 64 + col] = dd[r] + bv;
                else      x16o[(size_t)g2 * 64 + col] = (_Float16)(dd[r] + bv);
            }
        }
    }
    if (w == 3 && !last) {
        f32x4 dd; dd[0] = 0.f; dd[1] = 0.f; dd[2] = 0.f; dd[3] = 0.f;
        #pragma unroll
        for (int kc = 0; kc < 8; ++kc) {
            f16x8 b = *(const f16x8*)(Bf + ((32 + kc) * 64 + lane) * 8);
            dd = __builtin_amdgcn_mfma_f32_16x16x32_f16(A[kc], b, dd, 0, 0, 0);
        }
        if (m < 8) {
            float cv = cl[m];
            float* dp = (m < 4) ? elo : ero;
            #pragma unroll
            for (int r = 0; r < 4; ++r) {
                int g2 = r0 + kb * 4 + r;
                if (g2 < n) dp[(size_t)g2 * 4 + (m & 3)] = dd[r] + cv;
            }
        }
    }
}

// ================= launcher =================

extern "C" void kernel_launch(void* const* d_in, const int* in_sizes, int n_in,
                              void* d_out, int out_size, void* d_ws, size_t ws_size,
                              hipStream_t stream) {
    const float* feat = (const float*)d_in[0];
    const float* W    = (const float*)d_in[1];
    const float* al   = (const float*)d_in[2];
    const float* ar   = (const float*)d_in[3];
    const float* bias = (const float*)d_in[4];
    const int*   src  = (const int*)d_in[5];
    const int*   dst  = (const int*)d_in[6];
    float* out = (float*)d_out;

    const int N = in_sizes[0] / 64;   // 50000
    const int E = in_sizes[5];        // 500000
    const int L = 4;

    // workspace carve (float units)
    float* ws = (float*)d_ws;
    _Float16* x16A = (_Float16*)ws;                        // N*64 halves
    _Float16* x16B = (_Float16*)(ws + (size_t)N * 32);     // N*64 halves
    float* elA    = ws + (size_t)N * 64;                   // N*4
    float* erA    = elA + (size_t)N * 4;                   // N*4
    float* elB    = erA + (size_t)N * 4;                   // N*4
    float* erB    = elB + (size_t)N * 4;                   // N*4
    float* bsum   = erB + (size_t)N * 4;                   // 256
    float* WABall = bsum + 256;                            // 2048
    float* cl     = WABall + 2048;                         // 32
    _Float16* Bf    = (_Float16*)(cl + 32);                // 4*20480 halves
    _Float16* WABf0 = (_Float16*)((float*)Bf + 40960);     // 1024 halves
    int* rowptr  = (int*)((float*)WABf0 + 512);            // N+1
    int* cursor  = rowptr + (N + 1);                       // N
    int* deg     = cursor + N;                             // N
    int* csr_src = deg + N;                                // E
    int* bsums   = csr_src + E;                            // 32

    const int NB = (N + SCB - 1) / SCB;                    // 25

    // ---- prologue ----
    hipMemsetAsync(deg, 0, (size_t)N * sizeof(int), stream);
    int pro_total = E + 256 + 2048;
    k_pro<<<(pro_total + 255) / 256, 256, 0, stream>>>(
        dst, deg, W, al, ar, bias, bsum, WABall, E);
    k_packT<<<(4 * 20480 + 1024 + 24 + 255) / 256, 256, 0, stream>>>(
        W, WABall, bsum, Bf, WABf0, cl);
    k_scan1<<<NB, 256, 0, stream>>>(deg, bsums, N);
    k_scan23<<<NB, 256, 0, stream>>>(deg, bsums, rowptr, cursor, N, NB);
    k_scatter<<<(E + 255) / 256, 256, 0, stream>>>(src, dst, cursor, csr_src, E);

    // ---- layer 0 input (epoch A) ----
    k0<<<(N + 63) / 64, 256, 0, stream>>>(feat, WABf0, x16A, elA, erA, N);

    // ---- layers: fused aggregation + transform, ping-pong epochs ----
    _Float16* xin = x16A; float* eli = elA; float* eri = erA;
    _Float16* xot = x16B; float* elo = elB; float* ero = erB;
    for (int l = 0; l < L; ++l) {
        int last = (l == L - 1);
        k_layer<<<(N + 15) / 16, 256, 0, stream>>>(
            rowptr, csr_src, eli, eri, xin,
            Bf + (size_t)l * 20480, bsum + (size_t)l * 64,
            cl + (size_t)(l < 3 ? l : 0) * 8,
            xot, elo, ero, out, N, last);
        _Float16* tx = xin; xin = xot; xot = tx;
        float* te = eli; eli = elo; elo = te;
        te = eri; eri = ero; ero = te;
    }
}